// Round 12
// baseline (268.176 us; speedup 1.0000x reference)
//
#include <hip/hip_runtime.h>
#include <cstddef>

#define NB_HEAD 16
#define HEAD_DIM 64
#define D_MODEL 1024
#define BATCH 2
#define SEQ 2048
#define MROWS (BATCH * SEQ)  // 4096
#define NSPLIT 3             // key-axis split for attention TLP

typedef __bf16 bf16x8 __attribute__((ext_vector_type(8)));
typedef __bf16 bf16x4 __attribute__((ext_vector_type(4)));
typedef __bf16 bf16x2 __attribute__((ext_vector_type(2)));
typedef float  f32x4  __attribute__((ext_vector_type(4)));

#define XEL ((size_t)MROWS * D_MODEL)        // 4M elems per z
#define WEL ((size_t)D_MODEL * D_MODEL)      // 1M elems per z

// Q pre-scale: 1/sqrt(64) * log2(e) -> scores arrive in exp2 domain
#define QSCALE 0.18033688011112042f

// ---- chunk layouts: 16 rows x 32 k of bf16, 512 elems = 1 KB, ordered
// offset = ((k>>3)&3)*128 + (row&15)*8 + (k&7)  == lane*8+e with
// lane = grp*16+li, row=li, k = grp*8+e  (exact MFMA A/B fragment order).
static __device__ __forceinline__ size_t xchunk(int row, int k) {   // [row16][kc] grid, kc=0..31
    return ((size_t)(row >> 4) * 32 + (k >> 5)) * 512 + ((k >> 3) & 3) * 128 + (row & 15) * 8 + (k & 7);
}
static __device__ __forceinline__ size_t qkbase(int bh, int row16, int dc) {  // [bh][row16=128][dc=2]
    return ((size_t)(bh * 128 + row16) * 2 + dc) * 512;
}
static __device__ __forceinline__ size_t qkelem(int bh, int row, int d) {
    return qkbase(bh, row >> 4, d >> 5) + ((d >> 3) & 3) * 128 + (row & 15) * 8 + (d & 7);
}
static __device__ __forceinline__ size_t vbase(int bh, int d16, int kc) {     // [bh][d16=4][kc=64]
    return ((size_t)(bh * 4 + d16) * 64 + kc) * 512;
}
static __device__ __forceinline__ size_t velem(int bh, int d, int key) {
    return vbase(bh, d >> 4, key >> 5) + ((key >> 3) & 3) * 128 + (d & 15) * 8 + (key & 7);
}

static __device__ __forceinline__ void split_bf16(float x, __bf16& h, __bf16& l) {
    h = (__bf16)x;
    l = (__bf16)(x - (float)h);
}

// async global->LDS, 16B per lane; LDS dest is wave-uniform base, HW adds lane*16
static __device__ __forceinline__ void gload_lds16(const __bf16* g, __bf16* l) {
    __builtin_amdgcn_global_load_lds((const __attribute__((address_space(1))) void*)g,
                                     (__attribute__((address_space(3))) void*)l,
                                     16, 0, 0);
}

// ---------------------------------------------------------------------------
// W[K][N] fp32 -> chunk-format Wh/Wl (per z), rows = n, k = k.
// ---------------------------------------------------------------------------
__global__ __launch_bounds__(256) void conv_wt_kernel(
    const float* __restrict__ W0, const float* __restrict__ W1,
    const float* __restrict__ W2,
    __bf16* __restrict__ hi, __bf16* __restrict__ lo)
{
    __shared__ float tile[64][65];
    const int t  = threadIdx.x;
    const int k0 = blockIdx.x * 64;
    const int n0 = blockIdx.y * 64;
    const int z  = blockIdx.z;
    const float* W = (z == 0) ? W0 : ((z == 1) ? W1 : W2);
    __bf16* hz = hi + (size_t)z * WEL;
    __bf16* lz = lo + (size_t)z * WEL;

    #pragma unroll
    for (int p = 0; p < 4; ++p) {
        const int e = (p * 256 + t) * 4;
        const int r = e >> 6, c = e & 63;
        const float4 v = *(const float4*)(W + (size_t)(k0 + r) * D_MODEL + n0 + c);
        tile[r][c] = v.x; tile[r][c + 1] = v.y; tile[r][c + 2] = v.z; tile[r][c + 3] = v.w;
    }
    __syncthreads();
    #pragma unroll
    for (int p = 0; p < 4; ++p) {
        const int e = (p * 256 + t) * 4;        // 4 consecutive k for row n
        const int n = e >> 6, kc = e & 63;
        __bf16 h[4], l[4];
        #pragma unroll
        for (int u = 0; u < 4; ++u) split_bf16(tile[kc + u][n], h[u], l[u]);
        const size_t a = xchunk(n0 + n, k0 + kc);   // (k%4==0 -> 4 contiguous)
        *(bf16x4*)(hz + a) = (bf16x4){h[0], h[1], h[2], h[3]};
        *(bf16x4*)(lz + a) = (bf16x4){l[0], l[1], l[2], l[3]};
    }
}

// ---------------------------------------------------------------------------
// X fp32 -> chunk-format Xh/Xl per z, with 128-row strip skip.
// ---------------------------------------------------------------------------
__global__ __launch_bounds__(256) void conv_x_kernel(
    const float* __restrict__ X0, const float* __restrict__ X1,
    const float* __restrict__ X2,
    const int* __restrict__ q_len, const int* __restrict__ v_len,
    __bf16* __restrict__ xhi, __bf16* __restrict__ xlo)
{
    const int z = blockIdx.y;
    const size_t e = ((size_t)blockIdx.x * 256 + threadIdx.x) * 8;
    const int l = (int)(e >> 10), k = (int)(e & 1023);
    const int bb = l >> 11, lb = l & (SEQ - 1);
    const int len = (z == 0) ? q_len[bb] : v_len[bb];
    if (lb >= ((len + 127) & ~127)) return;

    const float* X = (z == 0) ? X0 : ((z == 1) ? X1 : X2);
    const float4 v0 = *(const float4*)(X + e);
    const float4 v1 = *(const float4*)(X + e + 4);
    const float xs[8] = {v0.x, v0.y, v0.z, v0.w, v1.x, v1.y, v1.z, v1.w};
    bf16x8 h8, l8;
    #pragma unroll
    for (int u = 0; u < 8; ++u) { __bf16 h_, l_; split_bf16(xs[u], h_, l_); h8[u] = h_; l8[u] = l_; }
    const size_t a = z * XEL + xchunk(l, k);    // k%8==0 -> contiguous 8
    *(bf16x8*)(xhi + a) = h8;
    *(bf16x8*)(xlo + a) = l8;
}

// ---------------------------------------------------------------------------
// Depth-2 pipelined MFMA projection. C = Xh Wh + Xh Wl + Xl Wh.
// 128x64 tile, BK=32, 4 waves 2x2. A staged via global_load_lds into a
// 3-deep LDS ring (3x16KB = 48KB, 3 blocks/CU); B (W) in a 3-set register
// ring. At step kc, A/B for kc+2 are issued; step end is a COUNTED
// s_waitcnt vmcnt(8) (keeps the 8 just-issued ops in flight, drains the
// kc+1 set) + raw s_barrier -- loads get 2 full compute phases of latency
// cover instead of 1 (the prior __syncthreads vmcnt(0) drain was the
// ~1.7k-cycle step-time bottleneck). Full unroll makes %3 indices static.
// Q outputs (z==0) pre-scaled by QSCALE (softmax exp2-domain fold).
// ---------------------------------------------------------------------------
__global__ __launch_bounds__(256, 3) void proj_mfma_kernel(
    const __bf16* __restrict__ Xhi, const __bf16* __restrict__ Xlo,
    const __bf16* __restrict__ Wchi, const __bf16* __restrict__ Wclo,
    const int* __restrict__ q_len, const int* __restrict__ v_len,
    __bf16* __restrict__ qch, __bf16* __restrict__ qcl,
    __bf16* __restrict__ kch, __bf16* __restrict__ kcl,
    __bf16* __restrict__ vch, __bf16* __restrict__ vcl)
{
    // 3-deep A ring: c 0..7 = A-hi (row16 idx), 8..15 = A-lo
    __shared__ __align__(16) __bf16 lds[3][16][512];   // 48 KB

    const int t    = threadIdx.x;
    const int wave = t >> 6, lane = t & 63;
    const int li   = lane & 15, grp = lane >> 4;
    const int wm   = wave >> 1, wn = wave & 1;
    const int m0   = blockIdx.x * 128;
    const int n0   = blockIdx.y * 64;
    const int z    = blockIdx.z;
    const int bb   = m0 >> 11;
    const int l0   = m0 & (SEQ - 1);
    const int need = (z == 0) ? q_len[bb] : v_len[bb];
    if (l0 >= need) return;

    const __bf16* Xh = Xhi + z * XEL;
    const __bf16* Xl = Xlo + z * XEL;
    const __bf16* Wh = Wchi + z * WEL;
    const __bf16* Wl = Wclo + z * WEL;

    // A staging sources: wave stages chunks c = u*4 + wave, u = 0..3
    const __bf16* gsA[4];
    #pragma unroll
    for (int u = 0; u < 4; ++u) {
        const int c = u * 4 + wave;
        const __bf16* src = (c < 8) ? Xh : Xl;
        const int idx = (m0 >> 4) + (c & 7);
        gsA[u] = src + (size_t)idx * 32 * 512 + (size_t)lane * 8;
    }

    // B direct-to-reg sources: rows (n0>>4)+wn*2+j, j=0,1
    const __bf16* gBh[2];
    const __bf16* gBl[2];
    #pragma unroll
    for (int j = 0; j < 2; ++j) {
        const int idx = (n0 >> 4) + wn * 2 + j;
        gBh[j] = Wh + (size_t)idx * 32 * 512 + (size_t)lane * 8;
        gBl[j] = Wl + (size_t)idx * 32 * 512 + (size_t)lane * 8;
    }

    // B register ring: 3 sets (1 in use + 2 in flight)
    bf16x8 bH[3][2], bL[3][2];

    auto STAGE_A = [&](int buf, int kc) {
        #pragma unroll
        for (int u = 0; u < 4; ++u)
            gload_lds16(gsA[u] + (size_t)kc * 512, &lds[buf][u * 4 + wave][0]);
    };
    auto LOAD_B = [&](int set, int kc) {
        #pragma unroll
        for (int j = 0; j < 2; ++j) {
            bH[set][j] = *(const bf16x8*)(gBh[j] + (size_t)kc * 512);
            bL[set][j] = *(const bf16x8*)(gBl[j] + (size_t)kc * 512);
        }
    };

    f32x4 acc[4][2] = {};

    // prologue: issue steps 0 and 1 (A->buf0/1, B->set0/1), drain step-0 set
    STAGE_A(0, 0); LOAD_B(0, 0);
    STAGE_A(1, 1); LOAD_B(1, 1);
    asm volatile("s_waitcnt vmcnt(8)" ::: "memory");   // step-0 A/B complete
    __builtin_amdgcn_s_barrier();
    __builtin_amdgcn_sched_barrier(0);

    #pragma unroll
    for (int kc = 0; kc < 32; ++kc) {
        const int cur = kc % 3;
        // ---- issue region (pinned): exactly 8 vmem ops for step kc+2
        if (kc + 2 < 32) {
            STAGE_A((kc + 2) % 3, kc + 2);
            LOAD_B((kc + 2) % 3, kc + 2);
        }
        __builtin_amdgcn_sched_barrier(0);

        bf16x8 ah[4], al4[4];
        #pragma unroll
        for (int i = 0; i < 4; ++i) {
            ah[i]  = *(const bf16x8*)&lds[cur][(wm << 2) + i][lane * 8];
            al4[i] = *(const bf16x8*)&lds[cur][8 + (wm << 2) + i][lane * 8];
        }
        #pragma unroll
        for (int j = 0; j < 2; ++j) {
            #pragma unroll
            for (int i = 0; i < 4; ++i) {
                acc[i][j] = __builtin_amdgcn_mfma_f32_16x16x32_bf16(ah[i],  bH[cur][j], acc[i][j], 0, 0, 0);
                acc[i][j] = __builtin_amdgcn_mfma_f32_16x16x32_bf16(ah[i],  bL[cur][j], acc[i][j], 0, 0, 0);
                acc[i][j] = __builtin_amdgcn_mfma_f32_16x16x32_bf16(al4[i], bH[cur][j], acc[i][j], 0, 0, 0);
            }
        }

        // ---- step end: counted drain (kc+1 set complete), raw barrier
        if (kc < 30) {
            asm volatile("s_waitcnt vmcnt(8)" ::: "memory");
            __builtin_amdgcn_s_barrier();
            __builtin_amdgcn_sched_barrier(0);
        } else if (kc == 30) {
            asm volatile("s_waitcnt vmcnt(0)" ::: "memory");
            __builtin_amdgcn_s_barrier();
            __builtin_amdgcn_sched_barrier(0);
        }
        // kc == 31: no barrier needed (epilogue follows)
    }

    // Epilogue: C/D col=li, row=grp*4+r. Write chunk-format outputs.
    #pragma unroll
    for (int j = 0; j < 2; ++j) {
        const int cg = n0 + wn * 32 + j * 16 + li;
        const int hd = cg >> 6, d = cg & 63;
        const int bhI = bb * NB_HEAD + hd;
        #pragma unroll
        for (int i = 0; i < 4; ++i) {
            #pragma unroll
            for (int r = 0; r < 4; ++r) {
                const int rg = m0 + wm * 64 + i * 16 + grp * 4 + r;
                const int lg = rg & (SEQ - 1);
                __bf16 h_, l_;
                if (z == 0) {
                    split_bf16(acc[i][j][r] * QSCALE, h_, l_);
                    const size_t a = qkelem(bhI, lg, d);
                    qch[a] = h_; qcl[a] = l_;
                } else if (z == 1) {
                    split_bf16(acc[i][j][r], h_, l_);
                    const size_t a = qkelem(bhI, lg, d);
                    kch[a] = h_; kcl[a] = l_;
                } else {
                    split_bf16(acc[i][j][r], h_, l_);
                    const size_t a = velem(bhI, d, lg);
                    vch[a] = h_; vcl[a] = l_;
                }
            }
        }
    }
}

// ---------------------------------------------------------------------------
// Barrier-free MFMA flash attention, key-axis split (NSPLIT=3), SWAPPED QK^T:
// S^T = mfma(K, Q) puts all keys of query li in-thread -> row-max is 15
// in-thread fmax + 2 shfl_xor; m is one scalar per s; P spills as packed
// b32 pairs. Empty splits write O=0, l=0, m=-1e30 (weight 0 in merge).
// ---------------------------------------------------------------------------
__global__ __launch_bounds__(256, 2) void attn_mfma_kernel(
    const __bf16* __restrict__ qch, const __bf16* __restrict__ qcl,
    const __bf16* __restrict__ kch, const __bf16* __restrict__ kcl,
    const __bf16* __restrict__ vch, const __bf16* __restrict__ vcl,
    const int* __restrict__ q_len, const int* __restrict__ v_len,
    float* __restrict__ Opart, float* __restrict__ Mbuf, float* __restrict__ Lbuf)
{
    __shared__ __align__(16) __bf16 Ps[128][72];

    const int t = threadIdx.x;
    const int wq = t >> 6, lane = t & 63;
    const int grp = lane >> 4, li = lane & 15;
    const int hh = blockIdx.x;
    const int split = (int)(blockIdx.y % NSPLIT);
    const int q0 = (int)(blockIdx.y / NSPLIT) * 128;
    const int b  = blockIdx.z;
    const int qlen = q_len[b], vlen = v_len[b];
    const int bh = b * NB_HEAD + hh;
    const int qbase = q0 + wq * 32;

    if (qbase >= qlen) return;   // merge writes zeros for q >= qlen

    bf16x8 onesv;
    #pragma unroll
    for (int u = 0; u < 8; ++u) onesv[u] = (__bf16)1.0f;

    // persistent Q fragments (pre-scaled by QSCALE)
    bf16x8 qh[2][2], ql[2][2];
    #pragma unroll
    for (int s = 0; s < 2; ++s)
        #pragma unroll
        for (int ks = 0; ks < 2; ++ks) {
            const size_t a = qkbase(bh, (qbase >> 4) + s, ks) + lane * 8;
            qh[s][ks] = *(const bf16x8*)(qch + a);
            ql[s][ks] = *(const bf16x8*)(qcl + a);
        }

    f32x4 O[2][4] = {};
    float m_s[2] = {-1e30f, -1e30f};   // per-thread: running max of query (li)
    float l_s[2][4];                   // per-thread: l of queries grp*4+r
    #pragma unroll
    for (int s = 0; s < 2; ++s)
        #pragma unroll
        for (int r = 0; r < 4; ++r) l_s[s][r] = 0.f;

    const int nktT = (vlen + 63) >> 6;                  // total 64-key tiles
    const int part = (nktT + NSPLIT - 1) / NSPLIT;      // tiles per split
    const int tBeg = split * part;
    const int tEnd = (nktT < tBeg + part) ? nktT : (tBeg + part);

    for (int tt = tBeg; tt < tEnd; ++tt) {
        const int k0 = tt * 64;
        const bool full = (k0 + 64 <= vlen);

        // ---- S^T = K Q^T (split): rows=key (grp*4+r), cols=query (li)
        f32x4 sacc[2][4] = {};
        #pragma unroll
        for (int ks = 0; ks < 2; ++ks) {
            bf16x8 kh_[4], kl_[4];
            #pragma unroll
            for (int j = 0; j < 4; ++j) {
                const size_t a = qkbase(bh, (k0 >> 4) + j, ks) + lane * 8;
                kh_[j] = *(const bf16x8*)(kch + a);
                kl_[j] = *(const bf16x8*)(kcl + a);
            }
            __builtin_amdgcn_s_setprio(1);
            #pragma unroll
            for (int j = 0; j < 4; ++j)
                #pragma unroll
                for (int s = 0; s < 2; ++s) {
                    sacc[s][j] = __builtin_amdgcn_mfma_f32_16x16x32_bf16(kh_[j], qh[s][ks], sacc[s][j], 0, 0, 0);
                    sacc[s][j] = __builtin_amdgcn_mfma_f32_16x16x32_bf16(kl_[j], qh[s][ks], sacc[s][j], 0, 0, 0);
                    sacc[s][j] = __builtin_amdgcn_mfma_f32_16x16x32_bf16(kh_[j], ql[s][ks], sacc[s][j], 0, 0, 0);
                }
            __builtin_amdgcn_s_setprio(0);
        }

        // ---- issue V frag loads early (hidden behind softmax VALU)
        bf16x8 vh_[2][4], vl_[2][4];
        #pragma unroll
        for (int ks = 0; ks < 2; ++ks)
            #pragma unroll
            for (int j = 0; j < 4; ++j) {
                const size_t a = vbase(bh, j, (k0 >> 5) + ks) + lane * 8;
                vh_[ks][j] = *(const bf16x8*)(vch + a);
                vl_[ks][j] = *(const bf16x8*)(vcl + a);
            }

        // ---- mask (partial tiles only) + row-max: 16 in-thread vals, 2 shfl
        float mx[2];
        int defer = 1;
        #pragma unroll
        for (int s = 0; s < 2; ++s) {
            if (!full) {
                #pragma unroll
                for (int j = 0; j < 4; ++j) {
                    const int keyb = k0 + j * 16 + grp * 4;
                    #pragma unroll
                    for (int r = 0; r < 4; ++r)
                        if (keyb + r >= vlen) sacc[s][j][r] = -1e30f;
                }
            }
            float m0_ = -1e30f;
            #pragma unroll
            for (int j = 0; j < 4; ++j)
                #pragma unroll
                for (int r = 0; r < 4; ++r) m0_ = fmaxf(m0_, sacc[s][j][r]);
            m0_ = fmaxf(m0_, __shfl_xor(m0_, 16));
            m0_ = fmaxf(m0_, __shfl_xor(m0_, 32));
            mx[s] = m0_;
            defer &= (m0_ - m_s[s] <= 8.f) ? 1 : 0;
        }

        // ---- rescale only when max moved past threshold (defer-max, THR=8)
        if (!__all(defer)) {
            #pragma unroll
            for (int s = 0; s < 2; ++s) {
                const float mn = fmaxf(m_s[s], mx[s]);
                const float alq = exp2f(m_s[s] - mn);   // at query=li
                m_s[s] = mn;
                #pragma unroll
                for (int r = 0; r < 4; ++r) {
                    const float alr = __shfl(alq, grp * 4 + r);  // al of query grp*4+r
                    l_s[s][r] *= alr;
                    #pragma unroll
                    for (int j = 0; j < 4; ++j) O[s][j][r] *= alr;
                }
            }
        }

        // ---- P = exp2(S - m), packed bf16 pairs to LDS (b32 stores)
        #pragma unroll
        for (int s = 0; s < 2; ++s) {
            const int row = wq * 32 + s * 16 + li;
            #pragma unroll
            for (int j = 0; j < 4; ++j) {
                const int col = j * 16 + grp * 4;
                bf16x2 w01, w23;
                w01[0] = (__bf16)exp2f(sacc[s][j][0] - m_s[s]);
                w01[1] = (__bf16)exp2f(sacc[s][j][1] - m_s[s]);
                w23[0] = (__bf16)exp2f(sacc[s][j][2] - m_s[s]);
                w23[1] = (__bf16)exp2f(sacc[s][j][3] - m_s[s]);
                *(bf16x2*)&Ps[row][col]     = w01;
                *(bf16x2*)&Ps[row][col + 2] = w23;
            }
        }
        asm volatile("s_waitcnt lgkmcnt(0)" ::: "memory");  // wave-private P strip

        // ---- l += rowsum(P) via MFMA-with-ones; O += P V (unchanged layout)
        bf16x8 pa[2][2];
        #pragma unroll
        for (int s = 0; s < 2; ++s)
            #pragma unroll
            for (int ks = 0; ks < 2; ++ks)
                pa[s][ks] = *(const bf16x8*)&Ps[wq * 32 + s * 16 + li][ks * 32 + grp * 8];

        __builtin_amdgcn_s_setprio(1);
        #pragma unroll
        for (int s = 0; s < 2; ++s) {
            f32x4 lsum = {};
            lsum = __builtin_amdgcn_mfma_f32_16x16x32_bf16(pa[s][0], onesv, lsum, 0, 0, 0);
            lsum = __builtin_amdgcn_mfma_f32_16x16x32_bf16(pa[s][1], onesv, lsum, 0, 0, 0);
            #pragma unroll
            for (int r = 0; r < 4; ++r) l_s[s][r] += lsum[r];
        }

        #pragma unroll
        for (int ks = 0; ks < 2; ++ks)
            #pragma unroll
            for (int j = 0; j < 4; ++j)
                #pragma unroll
                for (int s = 0; s < 2; ++s) {
                    O[s][j] = __builtin_amdgcn_mfma_f32_16x16x32_bf16(pa[s][ks], vh_[ks][j], O[s][j], 0, 0, 0);
                    O[s][j] = __builtin_amdgcn_mfma_f32_16x16x32_bf16(pa[s][ks], vl_[ks][j], O[s][j], 0, 0, 0);
                }
        __builtin_amdgcn_s_setprio(0);
    }

    // epilogue: unnormalized partial O; l from li==0 lanes (q=grp*4+r),
    // m (log2 domain) from grp==0 lanes (q=li).
    const size_t osplit = (size_t)split * MROWS * D_MODEL;
    #pragma unroll
    for (int s = 0; s < 2; ++s)
        #pragma unroll
        for (int r = 0; r < 4; ++r) {
            const int q = qbase + s * 16 + grp * 4 + r;
            if (q < qlen) {
                #pragma unroll
                for (int j = 0; j < 4; ++j)
                    Opart[osplit + ((size_t)b * SEQ + q) * D_MODEL + hh * HEAD_DIM + j * 16 + li] = O[s][j][r];
                if (li == 0) {
                    const size_t mi = (((size_t)split * BATCH + b) * NB_HEAD + hh) * SEQ + q;
                    Lbuf[mi] = l_s[s][r];
                }
            }
        }
    #pragma unroll
    for (int s = 0; s < 2; ++s) {
        const int q = qbase + s * 16 + li;
        if (grp == 0 && q < qlen) {
            const size_t mi = (((size_t)split * BATCH + b) * NB_HEAD + hh) * SEQ + q;
            Mbuf[mi] = m_s[s];
        }
    }
}

// ---------------------------------------------------------------------------
// Merge NSPLIT attention partials (m in log2 domain):
// O = sum_s O_s 2^{m_s-M} / sum_s l_s 2^{m_s-M}.
// ---------------------------------------------------------------------------
__global__ __launch_bounds__(256) void attn_merge_kernel(
    const float* __restrict__ Opart, const float* __restrict__ Mbuf,
    const float* __restrict__ Lbuf, const int* __restrict__ q_len,
    float* __restrict__ out)
{
    const int row = blockIdx.x;
    const int b = row >> 11, q = row & (SEQ - 1);
    const int col = threadIdx.x * 4;
    const int hh = col >> 6;
    const size_t oidx = (size_t)row * D_MODEL + col;

    float4 o = make_float4(0.f, 0.f, 0.f, 0.f);
    if (q < q_len[b]) {
        const size_t mlsz = (size_t)BATCH * NB_HEAD * SEQ;
        const size_t mi = ((size_t)b * NB_HEAD + hh) * SEQ + q;
        float ms[NSPLIT], ls[NSPLIT];
        float M = -1e30f;
        #pragma unroll
        for (int s = 0; s < NSPLIT; ++s) {
            ms[s] = Mbuf[s * mlsz + mi];
            ls[s] = Lbuf[s * mlsz + mi];
            M = fmaxf(M, ms[s]);
        }
        float denom = 0.f;
        float w[NSPLIT];
        #pragma unroll
        for (int s = 0; s < NSPLIT; ++s) {
            w[s] = exp2f(ms[s] - M);
            denom += ls[s] * w[s];
        }
        const float inv = 1.f / denom;
        float acc[4] = {0.f, 0.f, 0.f, 0.f};
        #pragma unroll
        for (int s = 0; s < NSPLIT; ++s) {
            const float4 a = *(const float4*)(Opart + (size_t)s * MROWS * D_MODEL + oidx);
            acc[0] += a.x * w[s]; acc[1] += a.y * w[s];
            acc[2] += a.z * w[s]; acc[3] += a.w * w[s];
        }
        o.x = acc[0] * inv; o.y = acc[1] * inv; o.z = acc[2] * inv; o.w = acc[3] * inv;
    }
    *(float4*)(out + oidx) = o;
}

extern "C" void kernel_launch(void* const* d_in, const int* in_sizes, int n_in,
                              void* d_out, int out_size, void* d_ws, size_t ws_size,
                              hipStream_t stream)
{
    (void)in_sizes; (void)n_in; (void)out_size; (void)ws_size;
    const float* Q_seq = (const float*)d_in[0];
    const float* K_seq = (const float*)d_in[1];
    const float* V_seq = (const float*)d_in[2];
    const int*   q_len = (const int*)d_in[3];
    const int*   v_len = (const int*)d_in[4];
    const float* WQ    = (const float*)d_in[5];
    const float* WK    = (const float*)d_in[6];
    const float* WV    = (const float*)d_in[7];
    float* out = (float*)d_out;

    // ws (__bf16 elems): W 2x3M, X 2x12M, q/k/v chunks 6x4M = 54M elems = 108 MB
    __bf16* wchi = (__bf16*)d_ws;
    __bf16* wclo = wchi + 3 * WEL;
    __bf16* xhi_ = wclo + 3 * WEL;
    __bf16* xlo_ = xhi_ + 3 * XEL;
    __bf16* qch_ = xlo_ + 3 * XEL;
    __bf16* qcl_ = qch_ + XEL;
    __bf16* kch_ = qcl_ + XEL;
    __bf16* kcl_ = kch_ + XEL;
    __bf16* vch_ = kcl_ + XEL;
    __bf16* vcl_ = vch_ + XEL;

    // attention partials reuse regions dead after proj:
    //   Opart (3 x 16 MB fp32) -> X-chunk region (48 MB); Mbuf/Lbuf -> W-chunk region
    float* Opart = (float*)xhi_;
    float* Mbuf  = (float*)wchi;
    float* Lbuf  = Mbuf + (size_t)NSPLIT * BATCH * NB_HEAD * SEQ;

    dim3 blk(256);

    dim3 cg(D_MODEL / 64, D_MODEL / 64, 3);     // (16,16,3)
    conv_wt_kernel<<<cg, blk, 0, stream>>>(WQ, WK, WV, wchi, wclo);

    dim3 xg((unsigned)(XEL / 2048), 3);         // (2048,3)
    conv_x_kernel<<<xg, blk, 0, stream>>>(Q_seq, K_seq, V_seq, q_len, v_len, xhi_, xlo_);

    dim3 pg(MROWS / 128, D_MODEL / 64, 3);      // (32,16,3) = 1536
    proj_mfma_kernel<<<pg, blk, 0, stream>>>(xhi_, xlo_, wchi, wclo, q_len, v_len,
                                             qch_, qcl_, kch_, kcl_, vch_, vcl_);

    dim3 ag(NB_HEAD, (SEQ / 128) * NSPLIT, BATCH);  // (16,48,2) = 1536
    attn_mfma_kernel<<<ag, blk, 0, stream>>>(qch_, qcl_, kch_, kcl_, vch_, vcl_,
                                             q_len, v_len, Opart, Mbuf, Lbuf);

    attn_merge_kernel<<<dim3(MROWS), blk, 0, stream>>>(Opart, Mbuf, Lbuf, q_len, out);
}

// Round 13
// 251.105 us; speedup vs baseline: 1.0680x; 1.0680x over previous
//
#include <hip/hip_runtime.h>
#include <cstddef>

#define NB_HEAD 16
#define HEAD_DIM 64
#define D_MODEL 1024
#define BATCH 2
#define SEQ 2048
#define MROWS (BATCH * SEQ)  // 4096
#define NSPLIT 3             // key-axis split for attention TLP

typedef __bf16 bf16x8 __attribute__((ext_vector_type(8)));
typedef __bf16 bf16x4 __attribute__((ext_vector_type(4)));
typedef __bf16 bf16x2 __attribute__((ext_vector_type(2)));
typedef float  f32x4  __attribute__((ext_vector_type(4)));

#define XEL ((size_t)MROWS * D_MODEL)        // 4M elems per z
#define WEL ((size_t)D_MODEL * D_MODEL)      // 1M elems per z

// Q pre-scale: 1/sqrt(64) * log2(e) -> scores arrive in exp2 domain
#define QSCALE 0.18033688011112042f

// ---- chunk layouts: 16 rows x 32 k of bf16, 512 elems = 1 KB, ordered
// offset = ((k>>3)&3)*128 + (row&15)*8 + (k&7)  == lane*8+e with
// lane = grp*16+li, row=li, k = grp*8+e  (exact MFMA A/B fragment order).
static __device__ __forceinline__ size_t xchunk(int row, int k) {   // [row16][kc] grid, kc=0..31
    return ((size_t)(row >> 4) * 32 + (k >> 5)) * 512 + ((k >> 3) & 3) * 128 + (row & 15) * 8 + (k & 7);
}
static __device__ __forceinline__ size_t qkbase(int bh, int row16, int dc) {  // [bh][row16=128][dc=2]
    return ((size_t)(bh * 128 + row16) * 2 + dc) * 512;
}
static __device__ __forceinline__ size_t qkelem(int bh, int row, int d) {
    return qkbase(bh, row >> 4, d >> 5) + ((d >> 3) & 3) * 128 + (row & 15) * 8 + (d & 7);
}
static __device__ __forceinline__ size_t vbase(int bh, int d16, int kc) {     // [bh][d16=4][kc=64]
    return ((size_t)(bh * 4 + d16) * 64 + kc) * 512;
}
static __device__ __forceinline__ size_t velem(int bh, int d, int key) {
    return vbase(bh, d >> 4, key >> 5) + ((key >> 3) & 3) * 128 + (d & 15) * 8 + (key & 7);
}

static __device__ __forceinline__ void split_bf16(float x, __bf16& h, __bf16& l) {
    h = (__bf16)x;
    l = (__bf16)(x - (float)h);
}

// async global->LDS, 16B per lane; LDS dest is wave-uniform base, HW adds lane*16
static __device__ __forceinline__ void gload_lds16(const __bf16* g, __bf16* l) {
    __builtin_amdgcn_global_load_lds((const __attribute__((address_space(1))) void*)g,
                                     (__attribute__((address_space(3))) void*)l,
                                     16, 0, 0);
}

// ---------------------------------------------------------------------------
// W[K][N] fp32 -> chunk-format Wh/Wl (per z), rows = n, k = k.
// ---------------------------------------------------------------------------
__global__ __launch_bounds__(256) void conv_wt_kernel(
    const float* __restrict__ W0, const float* __restrict__ W1,
    const float* __restrict__ W2,
    __bf16* __restrict__ hi, __bf16* __restrict__ lo)
{
    __shared__ float tile[64][65];
    const int t  = threadIdx.x;
    const int k0 = blockIdx.x * 64;
    const int n0 = blockIdx.y * 64;
    const int z  = blockIdx.z;
    const float* W = (z == 0) ? W0 : ((z == 1) ? W1 : W2);
    __bf16* hz = hi + (size_t)z * WEL;
    __bf16* lz = lo + (size_t)z * WEL;

    #pragma unroll
    for (int p = 0; p < 4; ++p) {
        const int e = (p * 256 + t) * 4;
        const int r = e >> 6, c = e & 63;
        const float4 v = *(const float4*)(W + (size_t)(k0 + r) * D_MODEL + n0 + c);
        tile[r][c] = v.x; tile[r][c + 1] = v.y; tile[r][c + 2] = v.z; tile[r][c + 3] = v.w;
    }
    __syncthreads();
    #pragma unroll
    for (int p = 0; p < 4; ++p) {
        const int e = (p * 256 + t) * 4;        // 4 consecutive k for row n
        const int n = e >> 6, kc = e & 63;
        __bf16 h[4], l[4];
        #pragma unroll
        for (int u = 0; u < 4; ++u) split_bf16(tile[kc + u][n], h[u], l[u]);
        const size_t a = xchunk(n0 + n, k0 + kc);   // (k%4==0 -> 4 contiguous)
        *(bf16x4*)(hz + a) = (bf16x4){h[0], h[1], h[2], h[3]};
        *(bf16x4*)(lz + a) = (bf16x4){l[0], l[1], l[2], l[3]};
    }
}

// ---------------------------------------------------------------------------
// X fp32 -> chunk-format Xh/Xl per z, with 128-row strip skip.
// ---------------------------------------------------------------------------
__global__ __launch_bounds__(256) void conv_x_kernel(
    const float* __restrict__ X0, const float* __restrict__ X1,
    const float* __restrict__ X2,
    const int* __restrict__ q_len, const int* __restrict__ v_len,
    __bf16* __restrict__ xhi, __bf16* __restrict__ xlo)
{
    const int z = blockIdx.y;
    const size_t e = ((size_t)blockIdx.x * 256 + threadIdx.x) * 8;
    const int l = (int)(e >> 10), k = (int)(e & 1023);
    const int bb = l >> 11, lb = l & (SEQ - 1);
    const int len = (z == 0) ? q_len[bb] : v_len[bb];
    if (lb >= ((len + 127) & ~127)) return;

    const float* X = (z == 0) ? X0 : ((z == 1) ? X1 : X2);
    const float4 v0 = *(const float4*)(X + e);
    const float4 v1 = *(const float4*)(X + e + 4);
    const float xs[8] = {v0.x, v0.y, v0.z, v0.w, v1.x, v1.y, v1.z, v1.w};
    bf16x8 h8, l8;
    #pragma unroll
    for (int u = 0; u < 8; ++u) { __bf16 h_, l_; split_bf16(xs[u], h_, l_); h8[u] = h_; l8[u] = l_; }
    const size_t a = z * XEL + xchunk(l, k);    // k%8==0 -> contiguous 8
    *(bf16x8*)(xhi + a) = h8;
    *(bf16x8*)(xlo + a) = l8;
}

// ---------------------------------------------------------------------------
// Depth-2 pipelined MFMA projection, ALL staging via global_load_lds (zero
// VGPR cost -- R12's B-register ring spilled at VGPR=76 and poisoned the
// experiment). C = Xh Wh + Xh Wl + Xl Wh. 128x64 tile, BK=32, 4 waves 2x2.
// 3-deep LDS ring of 24KB sets (A 16KB + B 8KB, R8's 24-chunk map) = 72KB,
// 2 blocks/CU. At step kc the set for kc+2 is issued (6 gload_lds/wave);
// step end = COUNTED s_waitcnt vmcnt(6) (keeps the just-issued 6 in flight,
// drains the kc+1 set) + raw s_barrier: loads get 2 full compute phases of
// cover instead of 1 (the vmcnt(0) drain was ~2300 cy/step of stall).
// Q outputs (z==0) pre-scaled by QSCALE (softmax exp2-domain fold).
// ---------------------------------------------------------------------------
__global__ __launch_bounds__(256, 2) void proj_mfma_kernel(
    const __bf16* __restrict__ Xhi, const __bf16* __restrict__ Xlo,
    const __bf16* __restrict__ Wchi, const __bf16* __restrict__ Wclo,
    const int* __restrict__ q_len, const int* __restrict__ v_len,
    __bf16* __restrict__ qch, __bf16* __restrict__ qcl,
    __bf16* __restrict__ kch, __bf16* __restrict__ kcl,
    __bf16* __restrict__ vch, __bf16* __restrict__ vcl)
{
    // ring of 3 sets, 24 chunks each: c 0..7 A-hi, 8..15 A-lo, 16..19 B-hi, 20..23 B-lo
    __shared__ __align__(16) __bf16 lds[3][24][512];   // 72 KB

    const int t    = threadIdx.x;
    const int wave = t >> 6, lane = t & 63;
    const int li   = lane & 15, grp = lane >> 4;
    const int wm   = wave >> 1, wn = wave & 1;
    const int m0   = blockIdx.x * 128;
    const int n0   = blockIdx.y * 64;
    const int z    = blockIdx.z;
    const int bb   = m0 >> 11;
    const int l0   = m0 & (SEQ - 1);
    const int need = (z == 0) ? q_len[bb] : v_len[bb];
    if (l0 >= need) return;

    const __bf16* Xh = Xhi + z * XEL;
    const __bf16* Xl = Xlo + z * XEL;
    const __bf16* Wh = Wchi + z * WEL;
    const __bf16* Wl = Wclo + z * WEL;

    // staging sources: wave stages chunks c = u*4 + wave, u = 0..5
    const __bf16* gs[6];
    #pragma unroll
    for (int u = 0; u < 6; ++u) {
        const int c = u * 4 + wave;
        const __bf16* src;
        int idx;
        if (c < 8)       { src = Xh; idx = (m0 >> 4) + c; }
        else if (c < 16) { src = Xl; idx = (m0 >> 4) + (c - 8); }
        else if (c < 20) { src = Wh; idx = (n0 >> 4) + (c - 16); }
        else             { src = Wl; idx = (n0 >> 4) + (c - 20); }
        gs[u] = src + (size_t)idx * 32 * 512 + (size_t)lane * 8;
    }

    auto STAGE = [&](int buf, int kc) {   // exactly 6 vmem ops per wave
        #pragma unroll
        for (int u = 0; u < 6; ++u)
            gload_lds16(gs[u] + (size_t)kc * 512, &lds[buf][u * 4 + wave][0]);
    };

    f32x4 acc[4][2] = {};

    // prologue: issue sets 0 and 1; drain set 0 (keep set 1's 6 in flight)
    STAGE(0, 0);
    STAGE(1, 1);
    asm volatile("s_waitcnt vmcnt(6)" ::: "memory");
    __builtin_amdgcn_s_barrier();
    __builtin_amdgcn_sched_barrier(0);

    #pragma unroll
    for (int kc = 0; kc < 32; ++kc) {
        const int cur = kc % 3;
        // ---- issue region (pinned): 6 vmem ops for step kc+2
        if (kc + 2 < 32) STAGE((kc + 2) % 3, kc + 2);
        __builtin_amdgcn_sched_barrier(0);

        bf16x8 ah[4], al4[4], bh2[2], bl2[2];
        #pragma unroll
        for (int i = 0; i < 4; ++i) {
            ah[i]  = *(const bf16x8*)&lds[cur][(wm << 2) + i][lane * 8];
            al4[i] = *(const bf16x8*)&lds[cur][8 + (wm << 2) + i][lane * 8];
        }
        #pragma unroll
        for (int j = 0; j < 2; ++j) {
            bh2[j] = *(const bf16x8*)&lds[cur][16 + (wn << 1) + j][lane * 8];
            bl2[j] = *(const bf16x8*)&lds[cur][20 + (wn << 1) + j][lane * 8];
        }
        #pragma unroll
        for (int j = 0; j < 2; ++j) {
            #pragma unroll
            for (int i = 0; i < 4; ++i) {
                acc[i][j] = __builtin_amdgcn_mfma_f32_16x16x32_bf16(ah[i],  bh2[j], acc[i][j], 0, 0, 0);
                acc[i][j] = __builtin_amdgcn_mfma_f32_16x16x32_bf16(ah[i],  bl2[j], acc[i][j], 0, 0, 0);
                acc[i][j] = __builtin_amdgcn_mfma_f32_16x16x32_bf16(al4[i], bh2[j], acc[i][j], 0, 0, 0);
            }
        }

        // ---- step end: counted drain (set kc+1 complete), raw barrier
        if (kc < 30) {
            asm volatile("s_waitcnt vmcnt(6)" ::: "memory");
            __builtin_amdgcn_s_barrier();
            __builtin_amdgcn_sched_barrier(0);
        } else if (kc == 30) {
            asm volatile("s_waitcnt vmcnt(0)" ::: "memory");
            __builtin_amdgcn_s_barrier();
            __builtin_amdgcn_sched_barrier(0);
        }
        // kc == 31: epilogue follows, no barrier needed
    }

    // Epilogue: C/D col=li, row=grp*4+r. Write chunk-format outputs.
    #pragma unroll
    for (int j = 0; j < 2; ++j) {
        const int cg = n0 + wn * 32 + j * 16 + li;
        const int hd = cg >> 6, d = cg & 63;
        const int bhI = bb * NB_HEAD + hd;
        #pragma unroll
        for (int i = 0; i < 4; ++i) {
            #pragma unroll
            for (int r = 0; r < 4; ++r) {
                const int rg = m0 + wm * 64 + i * 16 + grp * 4 + r;
                const int lg = rg & (SEQ - 1);
                __bf16 h_, l_;
                if (z == 0) {
                    split_bf16(acc[i][j][r] * QSCALE, h_, l_);
                    const size_t a = qkelem(bhI, lg, d);
                    qch[a] = h_; qcl[a] = l_;
                } else if (z == 1) {
                    split_bf16(acc[i][j][r], h_, l_);
                    const size_t a = qkelem(bhI, lg, d);
                    kch[a] = h_; kcl[a] = l_;
                } else {
                    split_bf16(acc[i][j][r], h_, l_);
                    const size_t a = velem(bhI, d, lg);
                    vch[a] = h_; vcl[a] = l_;
                }
            }
        }
    }
}

// ---------------------------------------------------------------------------
// Barrier-free MFMA flash attention, key-axis split (NSPLIT=3), SWAPPED QK^T:
// S^T = mfma(K, Q) puts all keys of query li in-thread -> row-max is 15
// in-thread fmax + 2 shfl_xor; m is one scalar per s; P spills as packed
// b32 pairs. Empty splits write O=0, l=0, m=-1e30 (weight 0 in merge).
// ---------------------------------------------------------------------------
__global__ __launch_bounds__(256, 2) void attn_mfma_kernel(
    const __bf16* __restrict__ qch, const __bf16* __restrict__ qcl,
    const __bf16* __restrict__ kch, const __bf16* __restrict__ kcl,
    const __bf16* __restrict__ vch, const __bf16* __restrict__ vcl,
    const int* __restrict__ q_len, const int* __restrict__ v_len,
    float* __restrict__ Opart, float* __restrict__ Mbuf, float* __restrict__ Lbuf)
{
    __shared__ __align__(16) __bf16 Ps[128][72];

    const int t = threadIdx.x;
    const int wq = t >> 6, lane = t & 63;
    const int grp = lane >> 4, li = lane & 15;
    const int hh = blockIdx.x;
    const int split = (int)(blockIdx.y % NSPLIT);
    const int q0 = (int)(blockIdx.y / NSPLIT) * 128;
    const int b  = blockIdx.z;
    const int qlen = q_len[b], vlen = v_len[b];
    const int bh = b * NB_HEAD + hh;
    const int qbase = q0 + wq * 32;

    if (qbase >= qlen) return;   // merge writes zeros for q >= qlen

    bf16x8 onesv;
    #pragma unroll
    for (int u = 0; u < 8; ++u) onesv[u] = (__bf16)1.0f;

    // persistent Q fragments (pre-scaled by QSCALE)
    bf16x8 qh[2][2], ql[2][2];
    #pragma unroll
    for (int s = 0; s < 2; ++s)
        #pragma unroll
        for (int ks = 0; ks < 2; ++ks) {
            const size_t a = qkbase(bh, (qbase >> 4) + s, ks) + lane * 8;
            qh[s][ks] = *(const bf16x8*)(qch + a);
            ql[s][ks] = *(const bf16x8*)(qcl + a);
        }

    f32x4 O[2][4] = {};
    float m_s[2] = {-1e30f, -1e30f};   // per-thread: running max of query (li)
    float l_s[2][4];                   // per-thread: l of queries grp*4+r
    #pragma unroll
    for (int s = 0; s < 2; ++s)
        #pragma unroll
        for (int r = 0; r < 4; ++r) l_s[s][r] = 0.f;

    const int nktT = (vlen + 63) >> 6;                  // total 64-key tiles
    const int part = (nktT + NSPLIT - 1) / NSPLIT;      // tiles per split
    const int tBeg = split * part;
    const int tEnd = (nktT < tBeg + part) ? nktT : (tBeg + part);

    for (int tt = tBeg; tt < tEnd; ++tt) {
        const int k0 = tt * 64;
        const bool full = (k0 + 64 <= vlen);

        // ---- S^T = K Q^T (split): rows=key (grp*4+r), cols=query (li)
        f32x4 sacc[2][4] = {};
        #pragma unroll
        for (int ks = 0; ks < 2; ++ks) {
            bf16x8 kh_[4], kl_[4];
            #pragma unroll
            for (int j = 0; j < 4; ++j) {
                const size_t a = qkbase(bh, (k0 >> 4) + j, ks) + lane * 8;
                kh_[j] = *(const bf16x8*)(kch + a);
                kl_[j] = *(const bf16x8*)(kcl + a);
            }
            __builtin_amdgcn_s_setprio(1);
            #pragma unroll
            for (int j = 0; j < 4; ++j)
                #pragma unroll
                for (int s = 0; s < 2; ++s) {
                    sacc[s][j] = __builtin_amdgcn_mfma_f32_16x16x32_bf16(kh_[j], qh[s][ks], sacc[s][j], 0, 0, 0);
                    sacc[s][j] = __builtin_amdgcn_mfma_f32_16x16x32_bf16(kl_[j], qh[s][ks], sacc[s][j], 0, 0, 0);
                    sacc[s][j] = __builtin_amdgcn_mfma_f32_16x16x32_bf16(kh_[j], ql[s][ks], sacc[s][j], 0, 0, 0);
                }
            __builtin_amdgcn_s_setprio(0);
        }

        // ---- issue V frag loads early (hidden behind softmax VALU)
        bf16x8 vh_[2][4], vl_[2][4];
        #pragma unroll
        for (int ks = 0; ks < 2; ++ks)
            #pragma unroll
            for (int j = 0; j < 4; ++j) {
                const size_t a = vbase(bh, j, (k0 >> 5) + ks) + lane * 8;
                vh_[ks][j] = *(const bf16x8*)(vch + a);
                vl_[ks][j] = *(const bf16x8*)(vcl + a);
            }

        // ---- mask (partial tiles only) + row-max: 16 in-thread vals, 2 shfl
        float mx[2];
        int defer = 1;
        #pragma unroll
        for (int s = 0; s < 2; ++s) {
            if (!full) {
                #pragma unroll
                for (int j = 0; j < 4; ++j) {
                    const int keyb = k0 + j * 16 + grp * 4;
                    #pragma unroll
                    for (int r = 0; r < 4; ++r)
                        if (keyb + r >= vlen) sacc[s][j][r] = -1e30f;
                }
            }
            float m0_ = -1e30f;
            #pragma unroll
            for (int j = 0; j < 4; ++j)
                #pragma unroll
                for (int r = 0; r < 4; ++r) m0_ = fmaxf(m0_, sacc[s][j][r]);
            m0_ = fmaxf(m0_, __shfl_xor(m0_, 16));
            m0_ = fmaxf(m0_, __shfl_xor(m0_, 32));
            mx[s] = m0_;
            defer &= (m0_ - m_s[s] <= 8.f) ? 1 : 0;
        }

        // ---- rescale only when max moved past threshold (defer-max, THR=8)
        if (!__all(defer)) {
            #pragma unroll
            for (int s = 0; s < 2; ++s) {
                const float mn = fmaxf(m_s[s], mx[s]);
                const float alq = exp2f(m_s[s] - mn);   // at query=li
                m_s[s] = mn;
                #pragma unroll
                for (int r = 0; r < 4; ++r) {
                    const float alr = __shfl(alq, grp * 4 + r);  // al of query grp*4+r
                    l_s[s][r] *= alr;
                    #pragma unroll
                    for (int j = 0; j < 4; ++j) O[s][j][r] *= alr;
                }
            }
        }

        // ---- P = exp2(S - m), packed bf16 pairs to LDS (b32 stores)
        #pragma unroll
        for (int s = 0; s < 2; ++s) {
            const int row = wq * 32 + s * 16 + li;
            #pragma unroll
            for (int j = 0; j < 4; ++j) {
                const int col = j * 16 + grp * 4;
                bf16x2 w01, w23;
                w01[0] = (__bf16)exp2f(sacc[s][j][0] - m_s[s]);
                w01[1] = (__bf16)exp2f(sacc[s][j][1] - m_s[s]);
                w23[0] = (__bf16)exp2f(sacc[s][j][2] - m_s[s]);
                w23[1] = (__bf16)exp2f(sacc[s][j][3] - m_s[s]);
                *(bf16x2*)&Ps[row][col]     = w01;
                *(bf16x2*)&Ps[row][col + 2] = w23;
            }
        }
        asm volatile("s_waitcnt lgkmcnt(0)" ::: "memory");  // wave-private P strip

        // ---- l += rowsum(P) via MFMA-with-ones; O += P V (unchanged layout)
        bf16x8 pa[2][2];
        #pragma unroll
        for (int s = 0; s < 2; ++s)
            #pragma unroll
            for (int ks = 0; ks < 2; ++ks)
                pa[s][ks] = *(const bf16x8*)&Ps[wq * 32 + s * 16 + li][ks * 32 + grp * 8];

        __builtin_amdgcn_s_setprio(1);
        #pragma unroll
        for (int s = 0; s < 2; ++s) {
            f32x4 lsum = {};
            lsum = __builtin_amdgcn_mfma_f32_16x16x32_bf16(pa[s][0], onesv, lsum, 0, 0, 0);
            lsum = __builtin_amdgcn_mfma_f32_16x16x32_bf16(pa[s][1], onesv, lsum, 0, 0, 0);
            #pragma unroll
            for (int r = 0; r < 4; ++r) l_s[s][r] += lsum[r];
        }

        #pragma unroll
        for (int ks = 0; ks < 2; ++ks)
            #pragma unroll
            for (int j = 0; j < 4; ++j)
                #pragma unroll
                for (int s = 0; s < 2; ++s) {
                    O[s][j] = __builtin_amdgcn_mfma_f32_16x16x32_bf16(pa[s][ks], vh_[ks][j], O[s][j], 0, 0, 0);
                    O[s][j] = __builtin_amdgcn_mfma_f32_16x16x32_bf16(pa[s][ks], vl_[ks][j], O[s][j], 0, 0, 0);
                }
        __builtin_amdgcn_s_setprio(0);
    }

    // epilogue: unnormalized partial O; l from li==0 lanes (q=grp*4+r),
    // m (log2 domain) from grp==0 lanes (q=li).
    const size_t osplit = (size_t)split * MROWS * D_MODEL;
    #pragma unroll
    for (int s = 0; s < 2; ++s)
        #pragma unroll
        for (int r = 0; r < 4; ++r) {
            const int q = qbase + s * 16 + grp * 4 + r;
            if (q < qlen) {
                #pragma unroll
                for (int j = 0; j < 4; ++j)
                    Opart[osplit + ((size_t)b * SEQ + q) * D_MODEL + hh * HEAD_DIM + j * 16 + li] = O[s][j][r];
                if (li == 0) {
                    const size_t mi = (((size_t)split * BATCH + b) * NB_HEAD + hh) * SEQ + q;
                    Lbuf[mi] = l_s[s][r];
                }
            }
        }
    #pragma unroll
    for (int s = 0; s < 2; ++s) {
        const int q = qbase + s * 16 + li;
        if (grp == 0 && q < qlen) {
            const size_t mi = (((size_t)split * BATCH + b) * NB_HEAD + hh) * SEQ + q;
            Mbuf[mi] = m_s[s];
        }
    }
}

// ---------------------------------------------------------------------------
// Merge NSPLIT attention partials (m in log2 domain):
// O = sum_s O_s 2^{m_s-M} / sum_s l_s 2^{m_s-M}.
// ---------------------------------------------------------------------------
__global__ __launch_bounds__(256) void attn_merge_kernel(
    const float* __restrict__ Opart, const float* __restrict__ Mbuf,
    const float* __restrict__ Lbuf, const int* __restrict__ q_len,
    float* __restrict__ out)
{
    const int row = blockIdx.x;
    const int b = row >> 11, q = row & (SEQ - 1);
    const int col = threadIdx.x * 4;
    const int hh = col >> 6;
    const size_t oidx = (size_t)row * D_MODEL + col;

    float4 o = make_float4(0.f, 0.f, 0.f, 0.f);
    if (q < q_len[b]) {
        const size_t mlsz = (size_t)BATCH * NB_HEAD * SEQ;
        const size_t mi = ((size_t)b * NB_HEAD + hh) * SEQ + q;
        float ms[NSPLIT], ls[NSPLIT];
        float M = -1e30f;
        #pragma unroll
        for (int s = 0; s < NSPLIT; ++s) {
            ms[s] = Mbuf[s * mlsz + mi];
            ls[s] = Lbuf[s * mlsz + mi];
            M = fmaxf(M, ms[s]);
        }
        float denom = 0.f;
        float w[NSPLIT];
        #pragma unroll
        for (int s = 0; s < NSPLIT; ++s) {
            w[s] = exp2f(ms[s] - M);
            denom += ls[s] * w[s];
        }
        const float inv = 1.f / denom;
        float acc[4] = {0.f, 0.f, 0.f, 0.f};
        #pragma unroll
        for (int s = 0; s < NSPLIT; ++s) {
            const float4 a = *(const float4*)(Opart + (size_t)s * MROWS * D_MODEL + oidx);
            acc[0] += a.x * w[s]; acc[1] += a.y * w[s];
            acc[2] += a.z * w[s]; acc[3] += a.w * w[s];
        }
        o.x = acc[0] * inv; o.y = acc[1] * inv; o.z = acc[2] * inv; o.w = acc[3] * inv;
    }
    *(float4*)(out + oidx) = o;
}

extern "C" void kernel_launch(void* const* d_in, const int* in_sizes, int n_in,
                              void* d_out, int out_size, void* d_ws, size_t ws_size,
                              hipStream_t stream)
{
    (void)in_sizes; (void)n_in; (void)out_size; (void)ws_size;
    const float* Q_seq = (const float*)d_in[0];
    const float* K_seq = (const float*)d_in[1];
    const float* V_seq = (const float*)d_in[2];
    const int*   q_len = (const int*)d_in[3];
    const int*   v_len = (const int*)d_in[4];
    const float* WQ    = (const float*)d_in[5];
    const float* WK    = (const float*)d_in[6];
    const float* WV    = (const float*)d_in[7];
    float* out = (float*)d_out;

    // ws (__bf16 elems): W 2x3M, X 2x12M, q/k/v chunks 6x4M = 54M elems = 108 MB
    __bf16* wchi = (__bf16*)d_ws;
    __bf16* wclo = wchi + 3 * WEL;
    __bf16* xhi_ = wclo + 3 * WEL;
    __bf16* xlo_ = xhi_ + 3 * XEL;
    __bf16* qch_ = xlo_ + 3 * XEL;
    __bf16* qcl_ = qch_ + XEL;
    __bf16* kch_ = qcl_ + XEL;
    __bf16* kcl_ = kch_ + XEL;
    __bf16* vch_ = kcl_ + XEL;
    __bf16* vcl_ = vch_ + XEL;

    // attention partials reuse regions dead after proj:
    //   Opart (3 x 16 MB fp32) -> X-chunk region (48 MB); Mbuf/Lbuf -> W-chunk region
    float* Opart = (float*)xhi_;
    float* Mbuf  = (float*)wchi;
    float* Lbuf  = Mbuf + (size_t)NSPLIT * BATCH * NB_HEAD * SEQ;

    dim3 blk(256);

    dim3 cg(D_MODEL / 64, D_MODEL / 64, 3);     // (16,16,3)
    conv_wt_kernel<<<cg, blk, 0, stream>>>(WQ, WK, WV, wchi, wclo);

    dim3 xg((unsigned)(XEL / 2048), 3);         // (2048,3)
    conv_x_kernel<<<xg, blk, 0, stream>>>(Q_seq, K_seq, V_seq, q_len, v_len, xhi_, xlo_);

    dim3 pg(MROWS / 128, D_MODEL / 64, 3);      // (32,16,3) = 1536
    proj_mfma_kernel<<<pg, blk, 0, stream>>>(xhi_, xlo_, wchi, wclo, q_len, v_len,
                                             qch_, qcl_, kch_, kcl_, vch_, vcl_);

    dim3 ag(NB_HEAD, (SEQ / 128) * NSPLIT, BATCH);  // (16,48,2) = 1536
    attn_mfma_kernel<<<ag, blk, 0, stream>>>(qch_, qcl_, kch_, kcl_, vch_, vcl_,
                                             q_len, v_len, Opart, Mbuf, Lbuf);

    attn_merge_kernel<<<dim3(MROWS), blk, 0, stream>>>(Opart, Mbuf, Lbuf, q_len, out);
}